// Round 2
// baseline (1045.471 us; speedup 1.0000x reference)
//
#include <hip/hip_runtime.h>
#include <hip/hip_bf16.h>

// MLA prefill: B=1, S=2048, H=4096, NH=16, QK_NOPE=128, QK_ROPE=64, V=128
// Device tensors are float32 (per reference dtypes); internal compute bf16 MFMA.

typedef short bf16x8 __attribute__((ext_vector_type(8)));
typedef float f32x4  __attribute__((ext_vector_type(4)));

// Load 8 contiguous elements as packed bf16 (uint4), converting if f32.
__device__ __forceinline__ uint4 ld8(const __hip_bfloat16* p) {
    return *(const uint4*)p;
}
__device__ __forceinline__ uint4 ld8(const float* p) {
    const float4 a = *(const float4*)p;
    const float4 b = *(const float4*)(p + 4);
    union { uint4 u; __hip_bfloat16 h[8]; } r;
    r.h[0] = __float2bfloat16(a.x); r.h[1] = __float2bfloat16(a.y);
    r.h[2] = __float2bfloat16(a.z); r.h[3] = __float2bfloat16(a.w);
    r.h[4] = __float2bfloat16(b.x); r.h[5] = __float2bfloat16(b.y);
    r.h[6] = __float2bfloat16(b.z); r.h[7] = __float2bfloat16(b.w);
    return r.u;
}

// ---------------------------------------------------------------------------
// C[M,N] = A[M,K] * B[N,K]^T. A,B f32 or bf16 in global; bf16 in LDS; fp32 acc.
// 128x128 tile, BK=64, 256 threads (2x2 waves of 64x64), MFMA 16x16x32 bf16.
// ---------------------------------------------------------------------------
template<typename TA, typename TB, bool OUT_F32>
__global__ __launch_bounds__(256)
void gemm_bt(const TA* __restrict__ A, const TB* __restrict__ B,
             void* __restrict__ C, int M, int N, int K) {
    __shared__ __align__(16) short As[128 * 72];
    __shared__ __align__(16) short Bs[128 * 72];

    const int tid  = threadIdx.x;
    const int lane = tid & 63;
    const int wave = tid >> 6;
    const int quad = lane >> 4;
    const int l16  = lane & 15;
    const int m0 = blockIdx.y * 128;
    const int n0 = blockIdx.x * 128;
    const int wm = (wave >> 1) * 64;
    const int wn = (wave & 1) * 64;

    f32x4 acc[4][4];
    for (int i = 0; i < 4; i++)
        for (int j = 0; j < 4; j++)
            acc[i][j] = f32x4{0.f, 0.f, 0.f, 0.f};

    const int ldr = tid >> 3;        // 0..31
    const int ldc = (tid & 7) * 8;   // 0,8,..,56

    for (int k0 = 0; k0 < K; k0 += 64) {
        for (int i = 0; i < 4; i++) {
            int row = i * 32 + ldr;
            uint4 v = ld8(A + (size_t)(m0 + row) * K + k0 + ldc);
            *(uint4*)(&As[row * 72 + ldc]) = v;
        }
        for (int i = 0; i < 4; i++) {
            int row = i * 32 + ldr;
            int gn = n0 + row;
            uint4 v = make_uint4(0u, 0u, 0u, 0u);
            if (gn < N) v = ld8(B + (size_t)gn * K + k0 + ldc);
            *(uint4*)(&Bs[row * 72 + ldc]) = v;
        }
        __syncthreads();
        for (int ks = 0; ks < 2; ks++) {
            bf16x8 af[4], bfr[4];
            for (int mi = 0; mi < 4; mi++) {
                int row = wm + mi * 16 + l16;
                af[mi] = *(const bf16x8*)(&As[row * 72 + ks * 32 + quad * 8]);
            }
            for (int ni = 0; ni < 4; ni++) {
                int row = wn + ni * 16 + l16;
                bfr[ni] = *(const bf16x8*)(&Bs[row * 72 + ks * 32 + quad * 8]);
            }
            for (int mi = 0; mi < 4; mi++)
                for (int ni = 0; ni < 4; ni++)
                    acc[mi][ni] = __builtin_amdgcn_mfma_f32_16x16x32_bf16(
                        af[mi], bfr[ni], acc[mi][ni], 0, 0, 0);
        }
        __syncthreads();
    }

    // C/D layout (verified m89/m91): col = lane&15, row = quad*4 + reg
    for (int mi = 0; mi < 4; mi++) {
        for (int ni = 0; ni < 4; ni++) {
            int col = n0 + wn + ni * 16 + l16;
            if (col >= N) continue;
            for (int r = 0; r < 4; r++) {
                int row = m0 + wm + mi * 16 + quad * 4 + r;
                float v = acc[mi][ni][r];
                if (OUT_F32) ((float*)C)[(size_t)row * N + col] = v;
                else ((__hip_bfloat16*)C)[(size_t)row * N + col] = __float2bfloat16(v);
            }
        }
    }
}

// ---------------------------------------------------------------------------
// Row-wise RMSNorm: f32 input (stride sx), f32 weight, bf16 output (stride sy)
// ---------------------------------------------------------------------------
__global__ __launch_bounds__(256)
void rmsnorm_k(const float* __restrict__ X, const float* __restrict__ w,
               __hip_bfloat16* __restrict__ Y, int W, int sx, int sy) {
    int row = blockIdx.x;
    const float* x = X + (size_t)row * sx;
    float ss = 0.f;
    for (int i = threadIdx.x; i < W; i += 256) { float v = x[i]; ss += v * v; }
    for (int off = 32; off; off >>= 1) ss += __shfl_down(ss, off);
    __shared__ float red[4];
    int lane = threadIdx.x & 63, wv = threadIdx.x >> 6;
    if (lane == 0) red[wv] = ss;
    __syncthreads();
    float tot = red[0] + red[1] + red[2] + red[3];
    float inv = rsqrtf(tot / (float)W + 1e-6f);
    for (int i = threadIdx.x; i < W; i += 256) {
        float v = x[i] * inv * w[i];
        Y[(size_t)row * sy + i] = __float2bfloat16(v);
    }
}

// ---------------------------------------------------------------------------
// Per-position RoPE (q in-place) + build kf[s][h] = concat(k_nope, roped k_pe)
// position_ids == arange(S), so pos = blockIdx.x.
// ---------------------------------------------------------------------------
__global__ __launch_bounds__(256)
void rope_assemble(__hip_bfloat16* __restrict__ q,          // [S,16,192] in-place
                   const __hip_bfloat16* __restrict__ kvexp,// [S,16,256]
                   const float* __restrict__ kvraw,         // [S,576] (cols 512.. = k_pe)
                   __hip_bfloat16* __restrict__ kf) {       // [S,16,192]
    int s = blockIdx.x;
    int tid = threadIdx.x;
    __shared__ float cs[32], sn[32];
    __shared__ __hip_bfloat16 kpe[64];
    if (tid < 32) {
        float inv = expf(-(float)tid * (logf(10000.0f) / 32.0f));
        float ang = (float)s * inv;
        cs[tid] = cosf(ang);
        sn[tid] = sinf(ang);
    }
    __syncthreads();
    if (tid < 32) {
        float x1 = kvraw[(size_t)s * 576 + 512 + tid];
        float x2 = kvraw[(size_t)s * 576 + 512 + 32 + tid];
        kpe[tid]      = __float2bfloat16(x1 * cs[tid] - x2 * sn[tid]);
        kpe[tid + 32] = __float2bfloat16(x2 * cs[tid] + x1 * sn[tid]);
    }
    for (int p = tid; p < 512; p += 256) {
        int h = p >> 5, j = p & 31;
        size_t base = (size_t)s * 3072 + h * 192 + 128;
        float x1 = __bfloat162float(q[base + j]);
        float x2 = __bfloat162float(q[base + j + 32]);
        q[base + j]      = __float2bfloat16(x1 * cs[j] - x2 * sn[j]);
        q[base + j + 32] = __float2bfloat16(x2 * cs[j] + x1 * sn[j]);
    }
    __syncthreads();
    for (int i = tid; i < 16 * 192; i += 256) {
        int h = i / 192, d = i % 192;
        __hip_bfloat16 v = (d < 128) ? kvexp[(size_t)s * 4096 + h * 256 + d]
                                     : kpe[d - 128];
        kf[(size_t)s * 3072 + h * 192 + d] = v;
    }
}

// ---------------------------------------------------------------------------
// vT[h][d][s] = kvexp[s][h*256 + 128 + d]
// ---------------------------------------------------------------------------
__global__ __launch_bounds__(256)
void transpose_v(const __hip_bfloat16* __restrict__ kvexp,
                 __hip_bfloat16* __restrict__ vT) {
    __shared__ __hip_bfloat16 t[64][65];
    int s0 = blockIdx.x * 64, d0 = blockIdx.y * 64, h = blockIdx.z;
    int c = threadIdx.x & 63;
    int r4 = threadIdx.x >> 6;
    for (int i = 0; i < 16; i++) {
        int r = r4 * 16 + i;
        t[r][c] = kvexp[(size_t)(s0 + r) * 4096 + h * 256 + 128 + d0 + c];
    }
    __syncthreads();
    for (int i = 0; i < 16; i++) {
        int r = r4 * 16 + i;   // d offset
        vT[((size_t)h * 128 + d0 + r) * 2048 + s0 + c] = t[c][r];
    }
}

// ---------------------------------------------------------------------------
// Flash-style causal attention per (64-row q tile, head). 256 thr = 4 waves.
// ---------------------------------------------------------------------------
__global__ __launch_bounds__(256)
void attn_kernel(const __hip_bfloat16* __restrict__ qb,   // [S,16,192]
                 const __hip_bfloat16* __restrict__ kf,   // [S,16,192]
                 const __hip_bfloat16* __restrict__ vT,   // [16,128,2048]
                 __hip_bfloat16* __restrict__ out) {      // [S,16,128]
    const int h  = blockIdx.y;
    const int qt = blockIdx.x;
    const int q0 = qt * 64;
    const int tid  = threadIdx.x;
    const int wave = tid >> 6;
    const int lane = tid & 63;
    const int quad = lane >> 4;
    const int l16  = lane & 15;

    __shared__ __align__(16) __hip_bfloat16 Ks[128 * 200];
    __shared__ __align__(16) __hip_bfloat16 Vs[128 * 136];
    __shared__ __align__(16) __hip_bfloat16 Ps[64 * 136];

    bf16x8 qfr[6];
    {
        int row = q0 + wave * 16 + l16;
        const __hip_bfloat16* qrow = qb + ((size_t)row * 16 + h) * 192;
        for (int ks = 0; ks < 6; ks++)
            qfr[ks] = *(const bf16x8*)(qrow + ks * 32 + quad * 8);
    }

    f32x4 o_acc[8];
    for (int i = 0; i < 8; i++) o_acc[i] = f32x4{0.f, 0.f, 0.f, 0.f};
    float m_i[4], l_i[4];
    for (int r = 0; r < 4; r++) { m_i[r] = -__builtin_inff(); l_i[r] = 0.f; }

    const float scale = 0.07216878364870322f;  // 192^-0.5
    const int nkt = qt / 2 + 1;

    for (int kt = 0; kt < nkt; kt++) {
        for (int i = 0; i < 12; i++) {
            int lin = i * 2048 + tid * 8;
            int row = lin / 192;
            int col = lin % 192;
            *(uint4*)(&Ks[row * 200 + col]) =
                *(const uint4*)(kf + ((size_t)(kt * 128 + row) * 16 + h) * 192 + col);
        }
        for (int i = 0; i < 8; i++) {
            int lin = i * 2048 + tid * 8;
            int row = lin >> 7;
            int col = lin & 127;
            *(uint4*)(&Vs[row * 136 + col]) =
                *(const uint4*)(vT + ((size_t)h * 128 + row) * 2048 + kt * 128 + col);
        }
        __syncthreads();

        f32x4 sc[8];
        for (int n = 0; n < 8; n++) sc[n] = f32x4{0.f, 0.f, 0.f, 0.f};
        for (int ks = 0; ks < 6; ks++)
            for (int n = 0; n < 8; n++) {
                bf16x8 kb = *(const bf16x8*)(&Ks[(n * 16 + l16) * 200 + ks * 32 + quad * 8]);
                sc[n] = __builtin_amdgcn_mfma_f32_16x16x32_bf16(qfr[ks], kb, sc[n], 0, 0, 0);
            }

        const bool last = (kt == nkt - 1);
        float tmax[4], rsum[4], alpha[4];
        for (int r = 0; r < 4; r++) tmax[r] = -__builtin_inff();
        for (int n = 0; n < 8; n++)
            for (int r = 0; r < 4; r++) {
                float v = sc[n][r] * scale;
                if (last && (kt * 128 + n * 16 + l16) > (q0 + wave * 16 + quad * 4 + r))
                    v = -__builtin_inff();
                sc[n][r] = v;
                tmax[r] = fmaxf(tmax[r], v);
            }
        for (int r = 0; r < 4; r++)
            for (int off = 1; off < 16; off <<= 1)
                tmax[r] = fmaxf(tmax[r], __shfl_xor(tmax[r], off));
        for (int r = 0; r < 4; r++) {
            float mn = fmaxf(m_i[r], tmax[r]);
            alpha[r] = expf(m_i[r] - mn);   // expf(-inf)=0 on first tile
            m_i[r] = mn;
            rsum[r] = 0.f;
        }
        for (int n = 0; n < 8; n++)
            for (int r = 0; r < 4; r++) {
                float p = expf(sc[n][r] - m_i[r]);
                sc[n][r] = p;
                rsum[r] += p;
            }
        for (int r = 0; r < 4; r++) {
            for (int off = 1; off < 16; off <<= 1)
                rsum[r] += __shfl_xor(rsum[r], off);
            l_i[r] = l_i[r] * alpha[r] + rsum[r];
        }
        for (int n = 0; n < 8; n++)
            for (int r = 0; r < 4; r++)
                Ps[(wave * 16 + quad * 4 + r) * 136 + n * 16 + l16] =
                    __float2bfloat16(sc[n][r]);
        for (int d = 0; d < 8; d++)
            for (int r = 0; r < 4; r++)
                o_acc[d][r] *= alpha[r];
        __syncthreads();

        for (int ks2 = 0; ks2 < 4; ks2++) {
            bf16x8 pa = *(const bf16x8*)(&Ps[(wave * 16 + l16) * 136 + ks2 * 32 + quad * 8]);
            for (int d = 0; d < 8; d++) {
                bf16x8 vb = *(const bf16x8*)(&Vs[(d * 16 + l16) * 136 + ks2 * 32 + quad * 8]);
                o_acc[d] = __builtin_amdgcn_mfma_f32_16x16x32_bf16(pa, vb, o_acc[d], 0, 0, 0);
            }
        }
        __syncthreads();
    }

    for (int d = 0; d < 8; d++)
        for (int r = 0; r < 4; r++) {
            int row = q0 + wave * 16 + quad * 4 + r;
            float v = o_acc[d][r] / l_i[r];
            out[((size_t)row * 16 + h) * 128 + d * 16 + l16] = __float2bfloat16(v);
        }
}

// ---------------------------------------------------------------------------
extern "C" void kernel_launch(void* const* d_in, const int* in_sizes, int n_in,
                              void* d_out, int out_size, void* d_ws, size_t ws_size,
                              hipStream_t stream) {
    const float* hidden = (const float*)d_in[0];
    // d_in[1] = position_ids == arange(2048); used implicitly as row idx
    const float* wq_a   = (const float*)d_in[2];
    const float* q_a_w  = (const float*)d_in[3];
    const float* wq_b   = (const float*)d_in[4];
    const float* wkv_a  = (const float*)d_in[5];
    const float* kv_a_w = (const float*)d_in[6];
    const float* wkv_b  = (const float*)d_in[7];
    const float* wo     = (const float*)d_in[8];
    float* out = (float*)d_out;

    char* ws = (char*)d_ws;
    float*          q_lat_raw = (float*)(ws + 0);                   // [2048,1536] f32
    __hip_bfloat16* kf        = (__hip_bfloat16*)(ws + 0);          // [2048,16,192] (reuse)
    float*          kv_raw    = (float*)(ws + 12582912);            // [2048,576] f32
    __hip_bfloat16* q_lat     = (__hip_bfloat16*)(ws + 17301504);   // [2048,1536]
    __hip_bfloat16* ckv       = (__hip_bfloat16*)(ws + 23592960);   // [2048,512]
    __hip_bfloat16* qb        = (__hip_bfloat16*)(ws + 25690112);   // [2048,16,192]
    __hip_bfloat16* kv_exp    = (__hip_bfloat16*)(ws + 38273024);   // [2048,16,256]
    __hip_bfloat16* vT        = (__hip_bfloat16*)(ws + 55050240);   // [16,128,2048]
    __hip_bfloat16* attn_o    = (__hip_bfloat16*)(ws + 63438848);   // [2048,16,128]

    dim3 blk(256);
    gemm_bt<float, float, true><<<dim3(12, 16), blk, 0, stream>>>(hidden, wq_a,  q_lat_raw, 2048, 1536, 4096);
    gemm_bt<float, float, true><<<dim3( 5, 16), blk, 0, stream>>>(hidden, wkv_a, kv_raw,    2048,  576, 4096);
    rmsnorm_k<<<2048, blk, 0, stream>>>(q_lat_raw, q_a_w,  q_lat, 1536, 1536, 1536);
    rmsnorm_k<<<2048, blk, 0, stream>>>(kv_raw,    kv_a_w, ckv,    512,  576,  512);
    gemm_bt<__hip_bfloat16, float, false><<<dim3(24, 16), blk, 0, stream>>>(q_lat, wq_b,  qb,     2048, 3072, 1536);
    gemm_bt<__hip_bfloat16, float, false><<<dim3(32, 16), blk, 0, stream>>>(ckv,   wkv_b, kv_exp, 2048, 4096,  512);
    rope_assemble<<<2048, blk, 0, stream>>>(qb, kv_exp, kv_raw, kf);
    transpose_v<<<dim3(32, 2, 16), blk, 0, stream>>>(kv_exp, vT);
    attn_kernel<<<dim3(32, 16), blk, 0, stream>>>(qb, kf, vT, attn_o);
    gemm_bt<__hip_bfloat16, float, true><<<dim3(32, 16), blk, 0, stream>>>(attn_o, wo, out, 2048, 4096, 2048);
}

// Round 3
// 694.204 us; speedup vs baseline: 1.5060x; 1.5060x over previous
//
#include <hip/hip_runtime.h>
#include <hip/hip_bf16.h>

// MLA prefill: B=1, S=2048, H=4096, NH=16, QK_NOPE=128, QK_ROPE=64, V=128
// Device tensors f32; internal compute bf16 MFMA.

typedef short bf16x8 __attribute__((ext_vector_type(8)));
typedef float f32x4  __attribute__((ext_vector_type(4)));

__device__ __forceinline__ uint4 ld8(const __hip_bfloat16* p) {
    return *(const uint4*)p;
}
__device__ __forceinline__ uint4 ld8(const float* p) {
    const float4 a = *(const float4*)p;
    const float4 b = *(const float4*)(p + 4);
    union { uint4 u; __hip_bfloat16 h[8]; } r;
    r.h[0] = __float2bfloat16(a.x); r.h[1] = __float2bfloat16(a.y);
    r.h[2] = __float2bfloat16(a.z); r.h[3] = __float2bfloat16(a.w);
    r.h[4] = __float2bfloat16(b.x); r.h[5] = __float2bfloat16(b.y);
    r.h[6] = __float2bfloat16(b.z); r.h[7] = __float2bfloat16(b.w);
    return r.u;
}

__global__ __launch_bounds__(256)
void zero_f32(float* __restrict__ p, int n4) {
    int i = blockIdx.x * 256 + threadIdx.x;
    if (i < n4) ((float4*)p)[i] = float4{0.f, 0.f, 0.f, 0.f};
}

// ---------------------------------------------------------------------------
// Fused first-stage GEMM: C[2048,2112] += hidden[2048,4096] * [wq_a;wkv_a]^T
// Split-K=4 (blockIdx.z), atomicAdd epilogue into zeroed accumulator.
// 2-stage register prefetch pipeline.
// ---------------------------------------------------------------------------
__global__ __launch_bounds__(256)
void gemm12_k(const float* __restrict__ hidden,
              const float* __restrict__ wq_a,    // [1536,4096]
              const float* __restrict__ wkv_a,   // [576,4096]
              float* __restrict__ C) {           // [2048,2112] accum
    __shared__ __align__(16) short As[128 * 72];
    __shared__ __align__(16) short Bs[128 * 72];

    const int tid  = threadIdx.x;
    const int lane = tid & 63;
    const int wave = tid >> 6;
    const int quad = lane >> 4;
    const int l16  = lane & 15;
    const int m0 = blockIdx.y * 128;
    const int n0 = blockIdx.x * 128;
    const int wm = (wave >> 1) * 64;
    const int wn = (wave & 1) * 64;
    const int kbeg = blockIdx.z * 1024;   // Kp = 1024, BK = 64 -> 16 iters

    f32x4 acc[4][4];
    for (int i = 0; i < 4; i++)
        for (int j = 0; j < 4; j++)
            acc[i][j] = f32x4{0.f, 0.f, 0.f, 0.f};

    const int ldr = tid >> 3;
    const int ldc = (tid & 7) * 8;

    uint4 av[4], bv[4];
    auto brow = [&](int gn) -> const float* {
        return gn < 1536 ? wq_a + (size_t)gn * 4096
                         : wkv_a + (size_t)(gn - 1536) * 4096;
    };
    auto load_tile = [&](int k0) {
        #pragma unroll
        for (int i = 0; i < 4; i++)
            av[i] = ld8(hidden + (size_t)(m0 + i * 32 + ldr) * 4096 + k0 + ldc);
        #pragma unroll
        for (int i = 0; i < 4; i++) {
            int gn = n0 + i * 32 + ldr;
            bv[i] = (gn < 2112) ? ld8(brow(gn) + k0 + ldc) : make_uint4(0u,0u,0u,0u);
        }
    };
    load_tile(kbeg);

    for (int kk = 0; kk < 16; kk++) {
        __syncthreads();
        #pragma unroll
        for (int i = 0; i < 4; i++) *(uint4*)(&As[(i * 32 + ldr) * 72 + ldc]) = av[i];
        #pragma unroll
        for (int i = 0; i < 4; i++) *(uint4*)(&Bs[(i * 32 + ldr) * 72 + ldc]) = bv[i];
        __syncthreads();
        if (kk + 1 < 16) load_tile(kbeg + (kk + 1) * 64);
        #pragma unroll
        for (int ks = 0; ks < 2; ks++) {
            bf16x8 af[4], bfr[4];
            #pragma unroll
            for (int mi = 0; mi < 4; mi++)
                af[mi] = *(const bf16x8*)(&As[(wm + mi * 16 + l16) * 72 + ks * 32 + quad * 8]);
            #pragma unroll
            for (int ni = 0; ni < 4; ni++)
                bfr[ni] = *(const bf16x8*)(&Bs[(wn + ni * 16 + l16) * 72 + ks * 32 + quad * 8]);
            #pragma unroll
            for (int mi = 0; mi < 4; mi++)
                #pragma unroll
                for (int ni = 0; ni < 4; ni++)
                    acc[mi][ni] = __builtin_amdgcn_mfma_f32_16x16x32_bf16(
                        af[mi], bfr[ni], acc[mi][ni], 0, 0, 0);
        }
    }

    for (int mi = 0; mi < 4; mi++)
        for (int ni = 0; ni < 4; ni++) {
            int col = n0 + wn + ni * 16 + l16;
            if (col >= 2112) continue;
            for (int r = 0; r < 4; r++) {
                int row = m0 + wm + mi * 16 + quad * 4 + r;
                atomicAdd(&C[(size_t)row * 2112 + col], acc[mi][ni][r]);
            }
        }
}

// ---------------------------------------------------------------------------
// Generic C[M,N] = A[M,K]*B[N,K]^T with register-prefetch pipeline.
// ---------------------------------------------------------------------------
template<typename TA, typename TB, bool OUT_F32>
__global__ __launch_bounds__(256)
void gemm_bt(const TA* __restrict__ A, const TB* __restrict__ B,
             void* __restrict__ C, int M, int N, int K) {
    __shared__ __align__(16) short As[128 * 72];
    __shared__ __align__(16) short Bs[128 * 72];

    const int tid  = threadIdx.x;
    const int lane = tid & 63;
    const int wave = tid >> 6;
    const int quad = lane >> 4;
    const int l16  = lane & 15;
    const int m0 = blockIdx.y * 128;
    const int n0 = blockIdx.x * 128;
    const int wm = (wave >> 1) * 64;
    const int wn = (wave & 1) * 64;

    f32x4 acc[4][4];
    for (int i = 0; i < 4; i++)
        for (int j = 0; j < 4; j++)
            acc[i][j] = f32x4{0.f, 0.f, 0.f, 0.f};

    const int ldr = tid >> 3;
    const int ldc = (tid & 7) * 8;
    const int nk = K / 64;

    uint4 av[4], bv[4];
    auto load_tile = [&](int k0) {
        #pragma unroll
        for (int i = 0; i < 4; i++)
            av[i] = ld8(A + (size_t)(m0 + i * 32 + ldr) * K + k0 + ldc);
        #pragma unroll
        for (int i = 0; i < 4; i++) {
            int gn = n0 + i * 32 + ldr;
            bv[i] = (gn < N) ? ld8(B + (size_t)gn * K + k0 + ldc) : make_uint4(0u,0u,0u,0u);
        }
    };
    load_tile(0);

    for (int kk = 0; kk < nk; kk++) {
        __syncthreads();
        #pragma unroll
        for (int i = 0; i < 4; i++) *(uint4*)(&As[(i * 32 + ldr) * 72 + ldc]) = av[i];
        #pragma unroll
        for (int i = 0; i < 4; i++) *(uint4*)(&Bs[(i * 32 + ldr) * 72 + ldc]) = bv[i];
        __syncthreads();
        if (kk + 1 < nk) load_tile((kk + 1) * 64);
        #pragma unroll
        for (int ks = 0; ks < 2; ks++) {
            bf16x8 af[4], bfr[4];
            #pragma unroll
            for (int mi = 0; mi < 4; mi++)
                af[mi] = *(const bf16x8*)(&As[(wm + mi * 16 + l16) * 72 + ks * 32 + quad * 8]);
            #pragma unroll
            for (int ni = 0; ni < 4; ni++)
                bfr[ni] = *(const bf16x8*)(&Bs[(wn + ni * 16 + l16) * 72 + ks * 32 + quad * 8]);
            #pragma unroll
            for (int mi = 0; mi < 4; mi++)
                #pragma unroll
                for (int ni = 0; ni < 4; ni++)
                    acc[mi][ni] = __builtin_amdgcn_mfma_f32_16x16x32_bf16(
                        af[mi], bfr[ni], acc[mi][ni], 0, 0, 0);
        }
    }

    // C/D layout: col = lane&15, row = quad*4 + reg
    for (int mi = 0; mi < 4; mi++)
        for (int ni = 0; ni < 4; ni++) {
            int col = n0 + wn + ni * 16 + l16;
            if (col >= N) continue;
            for (int r = 0; r < 4; r++) {
                int row = m0 + wm + mi * 16 + quad * 4 + r;
                float v = acc[mi][ni][r];
                if (OUT_F32) ((float*)C)[(size_t)row * N + col] = v;
                else ((__hip_bfloat16*)C)[(size_t)row * N + col] = __float2bfloat16(v);
            }
        }
}

// ---------------------------------------------------------------------------
// RMSNorm: f32 input (row stride sx), f32 weight, bf16 out (row stride sy)
// ---------------------------------------------------------------------------
__global__ __launch_bounds__(256)
void rmsnorm_k(const float* __restrict__ X, const float* __restrict__ w,
               __hip_bfloat16* __restrict__ Y, int W, int sx, int sy) {
    int row = blockIdx.x;
    const float* x = X + (size_t)row * sx;
    float ss = 0.f;
    for (int i = threadIdx.x; i < W; i += 256) { float v = x[i]; ss += v * v; }
    for (int off = 32; off; off >>= 1) ss += __shfl_down(ss, off);
    __shared__ float red[4];
    int lane = threadIdx.x & 63, wv = threadIdx.x >> 6;
    if (lane == 0) red[wv] = ss;
    __syncthreads();
    float tot = red[0] + red[1] + red[2] + red[3];
    float inv = rsqrtf(tot / (float)W + 1e-6f);
    for (int i = threadIdx.x; i < W; i += 256) {
        float v = x[i] * inv * w[i];
        Y[(size_t)row * sy + i] = __float2bfloat16(v);
    }
}

// ---------------------------------------------------------------------------
// RoPE (q in-place) + build kf = concat(k_nope, roped k_pe). pos = blockIdx.x.
// k_pe source: fused accum cols 2048..2111 (row stride 2112).
// ---------------------------------------------------------------------------
__global__ __launch_bounds__(256)
void rope_assemble(__hip_bfloat16* __restrict__ q,           // [S,16,192] in-place
                   const __hip_bfloat16* __restrict__ kvexp, // [S,16,256]
                   const float* __restrict__ fused,          // [S,2112]
                   __hip_bfloat16* __restrict__ kf) {        // [S,16,192]
    int s = blockIdx.x;
    int tid = threadIdx.x;
    __shared__ float cs[32], sn[32];
    __shared__ __hip_bfloat16 kpe[64];
    if (tid < 32) {
        float inv = expf(-(float)tid * (logf(10000.0f) / 32.0f));
        float ang = (float)s * inv;
        cs[tid] = cosf(ang);
        sn[tid] = sinf(ang);
    }
    __syncthreads();
    if (tid < 32) {
        float x1 = fused[(size_t)s * 2112 + 2048 + tid];
        float x2 = fused[(size_t)s * 2112 + 2048 + 32 + tid];
        kpe[tid]      = __float2bfloat16(x1 * cs[tid] - x2 * sn[tid]);
        kpe[tid + 32] = __float2bfloat16(x2 * cs[tid] + x1 * sn[tid]);
    }
    for (int p = tid; p < 512; p += 256) {
        int h = p >> 5, j = p & 31;
        size_t base = (size_t)s * 3072 + h * 192 + 128;
        float x1 = __bfloat162float(q[base + j]);
        float x2 = __bfloat162float(q[base + j + 32]);
        q[base + j]      = __float2bfloat16(x1 * cs[j] - x2 * sn[j]);
        q[base + j + 32] = __float2bfloat16(x2 * cs[j] + x1 * sn[j]);
    }
    __syncthreads();
    for (int i = tid; i < 16 * 192; i += 256) {
        int h = i / 192, d = i % 192;
        __hip_bfloat16 v = (d < 128) ? kvexp[(size_t)s * 4096 + h * 256 + d]
                                     : kpe[d - 128];
        kf[(size_t)s * 3072 + h * 192 + d] = v;
    }
}

// ---------------------------------------------------------------------------
// vT[h][d][s] = kvexp[s][h*256 + 128 + d]
// ---------------------------------------------------------------------------
__global__ __launch_bounds__(256)
void transpose_v(const __hip_bfloat16* __restrict__ kvexp,
                 __hip_bfloat16* __restrict__ vT) {
    __shared__ __hip_bfloat16 t[64][65];
    int s0 = blockIdx.x * 64, d0 = blockIdx.y * 64, h = blockIdx.z;
    int c = threadIdx.x & 63;
    int r4 = threadIdx.x >> 6;
    for (int i = 0; i < 16; i++) {
        int r = r4 * 16 + i;
        t[r][c] = kvexp[(size_t)(s0 + r) * 4096 + h * 256 + 128 + d0 + c];
    }
    __syncthreads();
    for (int i = 0; i < 16; i++) {
        int r = r4 * 16 + i;
        vT[((size_t)h * 128 + d0 + r) * 2048 + s0 + c] = t[c][r];
    }
}

// ---------------------------------------------------------------------------
// Flash-style causal attention per (64-row q tile, head). 256 thr = 4 waves.
// ---------------------------------------------------------------------------
__global__ __launch_bounds__(256)
void attn_kernel(const __hip_bfloat16* __restrict__ qb,   // [S,16,192]
                 const __hip_bfloat16* __restrict__ kf,   // [S,16,192]
                 const __hip_bfloat16* __restrict__ vT,   // [16,128,2048]
                 __hip_bfloat16* __restrict__ out) {      // [S,16,128]
    const int h  = blockIdx.y;
    const int qt = blockIdx.x;
    const int q0 = qt * 64;
    const int tid  = threadIdx.x;
    const int wave = tid >> 6;
    const int lane = tid & 63;
    const int quad = lane >> 4;
    const int l16  = lane & 15;

    __shared__ __align__(16) __hip_bfloat16 Ks[128 * 200];
    __shared__ __align__(16) __hip_bfloat16 Vs[128 * 136];
    __shared__ __align__(16) __hip_bfloat16 Ps[64 * 136];

    bf16x8 qfr[6];
    {
        int row = q0 + wave * 16 + l16;
        const __hip_bfloat16* qrow = qb + ((size_t)row * 16 + h) * 192;
        for (int ks = 0; ks < 6; ks++)
            qfr[ks] = *(const bf16x8*)(qrow + ks * 32 + quad * 8);
    }

    f32x4 o_acc[8];
    for (int i = 0; i < 8; i++) o_acc[i] = f32x4{0.f, 0.f, 0.f, 0.f};
    float m_i[4], l_i[4];
    for (int r = 0; r < 4; r++) { m_i[r] = -__builtin_inff(); l_i[r] = 0.f; }

    const float scale = 0.07216878364870322f;  // 192^-0.5
    const int nkt = qt / 2 + 1;

    for (int kt = 0; kt < nkt; kt++) {
        for (int i = 0; i < 12; i++) {
            int lin = i * 2048 + tid * 8;
            int row = lin / 192;
            int col = lin % 192;
            *(uint4*)(&Ks[row * 200 + col]) =
                *(const uint4*)(kf + ((size_t)(kt * 128 + row) * 16 + h) * 192 + col);
        }
        for (int i = 0; i < 8; i++) {
            int lin = i * 2048 + tid * 8;
            int row = lin >> 7;
            int col = lin & 127;
            *(uint4*)(&Vs[row * 136 + col]) =
                *(const uint4*)(vT + ((size_t)h * 128 + row) * 2048 + kt * 128 + col);
        }
        __syncthreads();

        f32x4 sc[8];
        for (int n = 0; n < 8; n++) sc[n] = f32x4{0.f, 0.f, 0.f, 0.f};
        for (int ks = 0; ks < 6; ks++)
            for (int n = 0; n < 8; n++) {
                bf16x8 kb = *(const bf16x8*)(&Ks[(n * 16 + l16) * 200 + ks * 32 + quad * 8]);
                sc[n] = __builtin_amdgcn_mfma_f32_16x16x32_bf16(qfr[ks], kb, sc[n], 0, 0, 0);
            }

        const bool last = (kt == nkt - 1);
        float tmax[4], rsum[4], alpha[4];
        for (int r = 0; r < 4; r++) tmax[r] = -__builtin_inff();
        for (int n = 0; n < 8; n++)
            for (int r = 0; r < 4; r++) {
                float v = sc[n][r] * scale;
                if (last && (kt * 128 + n * 16 + l16) > (q0 + wave * 16 + quad * 4 + r))
                    v = -__builtin_inff();
                sc[n][r] = v;
                tmax[r] = fmaxf(tmax[r], v);
            }
        for (int r = 0; r < 4; r++)
            for (int off = 1; off < 16; off <<= 1)
                tmax[r] = fmaxf(tmax[r], __shfl_xor(tmax[r], off));
        for (int r = 0; r < 4; r++) {
            float mn = fmaxf(m_i[r], tmax[r]);
            alpha[r] = expf(m_i[r] - mn);
            m_i[r] = mn;
            rsum[r] = 0.f;
        }
        for (int n = 0; n < 8; n++)
            for (int r = 0; r < 4; r++) {
                float p = expf(sc[n][r] - m_i[r]);
                sc[n][r] = p;
                rsum[r] += p;
            }
        for (int r = 0; r < 4; r++) {
            for (int off = 1; off < 16; off <<= 1)
                rsum[r] += __shfl_xor(rsum[r], off);
            l_i[r] = l_i[r] * alpha[r] + rsum[r];
        }
        for (int n = 0; n < 8; n++)
            for (int r = 0; r < 4; r++)
                Ps[(wave * 16 + quad * 4 + r) * 136 + n * 16 + l16] =
                    __float2bfloat16(sc[n][r]);
        for (int d = 0; d < 8; d++)
            for (int r = 0; r < 4; r++)
                o_acc[d][r] *= alpha[r];
        __syncthreads();

        for (int ks2 = 0; ks2 < 4; ks2++) {
            bf16x8 pa = *(const bf16x8*)(&Ps[(wave * 16 + l16) * 136 + ks2 * 32 + quad * 8]);
            for (int d = 0; d < 8; d++) {
                bf16x8 vb = *(const bf16x8*)(&Vs[(d * 16 + l16) * 136 + ks2 * 32 + quad * 8]);
                o_acc[d] = __builtin_amdgcn_mfma_f32_16x16x32_bf16(pa, vb, o_acc[d], 0, 0, 0);
            }
        }
        __syncthreads();
    }

    for (int d = 0; d < 8; d++)
        for (int r = 0; r < 4; r++) {
            int row = q0 + wave * 16 + quad * 4 + r;
            float v = o_acc[d][r] / l_i[r];
            out[((size_t)row * 16 + h) * 128 + d * 16 + l16] = __float2bfloat16(v);
        }
}

// ---------------------------------------------------------------------------
extern "C" void kernel_launch(void* const* d_in, const int* in_sizes, int n_in,
                              void* d_out, int out_size, void* d_ws, size_t ws_size,
                              hipStream_t stream) {
    const float* hidden = (const float*)d_in[0];
    const float* wq_a   = (const float*)d_in[2];
    const float* q_a_w  = (const float*)d_in[3];
    const float* wq_b   = (const float*)d_in[4];
    const float* wkv_a  = (const float*)d_in[5];
    const float* kv_a_w = (const float*)d_in[6];
    const float* wkv_b  = (const float*)d_in[7];
    const float* wo     = (const float*)d_in[8];
    float* out = (float*)d_out;

    char* ws = (char*)d_ws;
    float*          fused  = (float*)(ws + 0);                   // [2048,2112] f32 accum
    __hip_bfloat16* vT     = (__hip_bfloat16*)(ws + 0);          // [16,128,2048] (reuse after rope)
    __hip_bfloat16* attn_o = (__hip_bfloat16*)(ws + 8388608);    // [2048,16,128] (reuse)
    __hip_bfloat16* q_lat  = (__hip_bfloat16*)(ws + 17301504);   // [2048,1536]
    __hip_bfloat16* ckv    = (__hip_bfloat16*)(ws + 23592960);   // [2048,512]
    __hip_bfloat16* qb     = (__hip_bfloat16*)(ws + 25690112);   // [2048,16,192]
    __hip_bfloat16* kv_exp = (__hip_bfloat16*)(ws + 38273024);   // [2048,16,256]
    __hip_bfloat16* kf     = (__hip_bfloat16*)(ws + 55050240);   // [2048,16,192]

    dim3 blk(256);
    zero_f32<<<dim3((2048 * 2112 / 4 + 255) / 256), blk, 0, stream>>>(fused, 2048 * 2112 / 4);
    gemm12_k<<<dim3(17, 16, 4), blk, 0, stream>>>(hidden, wq_a, wkv_a, fused);
    rmsnorm_k<<<2048, blk, 0, stream>>>(fused,        q_a_w,  q_lat, 1536, 2112, 1536);
    rmsnorm_k<<<2048, blk, 0, stream>>>(fused + 1536, kv_a_w, ckv,    512, 2112,  512);
    gemm_bt<__hip_bfloat16, float, false><<<dim3(24, 16), blk, 0, stream>>>(q_lat, wq_b,  qb,     2048, 3072, 1536);
    gemm_bt<__hip_bfloat16, float, false><<<dim3(32, 16), blk, 0, stream>>>(ckv,   wkv_b, kv_exp, 2048, 4096,  512);
    rope_assemble<<<2048, blk, 0, stream>>>(qb, kv_exp, fused, kf);
    transpose_v<<<dim3(32, 2, 16), blk, 0, stream>>>(kv_exp, vT);
    attn_kernel<<<dim3(32, 16), blk, 0, stream>>>(qb, kf, vT, attn_o);
    gemm_bt<__hip_bfloat16, float, true><<<dim3(32, 16), blk, 0, stream>>>(attn_o, wo, out, 2048, 4096, 2048);
}

// Round 4
// 521.204 us; speedup vs baseline: 2.0059x; 1.3319x over previous
//
#include <hip/hip_runtime.h>
#include <hip/hip_bf16.h>

// MLA prefill: B=1, S=2048, H=4096, NH=16, QK_NOPE=128, QK_ROPE=64, V=128
// Device tensors f32; GEMM operands pre-converted to bf16; m97-style
// global_load_lds staging with XOR source-swizzle (conflict-free ds_read_b128).

typedef short bf16x8 __attribute__((ext_vector_type(8)));
typedef float f32x4  __attribute__((ext_vector_type(4)));

#if __has_builtin(__builtin_amdgcn_global_load_lds)
#define USE_GLL 1
#else
#define USE_GLL 0
#endif

__device__ __forceinline__ void stage16(const void* g, void* l) {
#if USE_GLL
    __builtin_amdgcn_global_load_lds(
        (__attribute__((address_space(1))) void*)(g),
        (__attribute__((address_space(3))) void*)(l), 16, 0, 0);
#else
    *(uint4*)l = *(const uint4*)g;
#endif
}

// ---------------------------------------------------------------------------
// Elementwise helpers
// ---------------------------------------------------------------------------
__global__ __launch_bounds__(256)
void cvt_bf16(const float* __restrict__ s, __hip_bfloat16* __restrict__ d, int nq) {
    int i = blockIdx.x * 256 + threadIdx.x;
    if (i >= nq) return;
    float4 v = ((const float4*)s)[i];
    union { uint2 u; __hip_bfloat16 h[4]; } r;
    r.h[0] = __float2bfloat16(v.x); r.h[1] = __float2bfloat16(v.y);
    r.h[2] = __float2bfloat16(v.z); r.h[3] = __float2bfloat16(v.w);
    ((uint2*)d)[i] = r.u;
}

__global__ __launch_bounds__(256)
void zero_f32(float* __restrict__ p, int n4) {
    int i = blockIdx.x * 256 + threadIdx.x;
    if (i < n4) ((float4*)p)[i] = float4{0.f, 0.f, 0.f, 0.f};
}

__global__ __launch_bounds__(256)
void zero_u4(uint4* __restrict__ p, int n) {
    int i = blockIdx.x * 256 + threadIdx.x;
    if (i < n) p[i] = make_uint4(0u, 0u, 0u, 0u);
}

// kpe[r*64+c] = fused[r*2112 + 2048 + c]  (compact k_pe slice, frees fused)
__global__ __launch_bounds__(256)
void kpe_copy(const float* __restrict__ fused, float* __restrict__ kpe) {
    int i = blockIdx.x * 256 + threadIdx.x;   // 131072 total
    int r = i >> 6, c = i & 63;
    kpe[i] = fused[(size_t)r * 2112 + 2048 + c];
}

// ---------------------------------------------------------------------------
// m97-style GEMM: C[M,*] = A[M,K] * B[*,K]^T, bf16 in, fp32 acc.
// 128x128 tile, BK=64, 256 thr. global_load_lds 16B staging, XOR src swizzle:
// LDS chunk c of row r holds global 16B-chunk c^(r&7)  (rows 128B, no pad).
// OUTMODE: 0 = bf16 store, 1 = f32 store, 2 = f32 atomicAdd (split-K).
// ---------------------------------------------------------------------------
template<int OUTMODE>
__global__ __launch_bounds__(256)
void gemm_lds(const __hip_bfloat16* __restrict__ A,
              const __hip_bfloat16* __restrict__ B,
              void* __restrict__ C,
              int K, int Cld, int Nlim, int ksteps) {
    __shared__ __align__(16) short As[128 * 64];
    __shared__ __align__(16) short Bs[128 * 64];

    const int tid  = threadIdx.x;
    const int lane = tid & 63;
    const int wave = tid >> 6;
    const int quad = lane >> 4;
    const int l16  = lane & 15;
    const int m0 = blockIdx.y * 128;
    const int n0 = blockIdx.x * 128;
    const int wm = (wave >> 1) * 64;
    const int wn = (wave & 1) * 64;
    const int kbeg = blockIdx.z * ksteps * 64;

    const int lrow = lane >> 3;        // 0..7 row-within-group
    const int lchk = lane & 7;         // 0..7 dst chunk
    const int sb   = (lchk ^ lrow) * 16;  // swizzled source byte offset in row

    f32x4 acc[4][4];
    #pragma unroll
    for (int i = 0; i < 4; i++)
        #pragma unroll
        for (int j = 0; j < 4; j++)
            acc[i][j] = f32x4{0.f, 0.f, 0.f, 0.f};

    const size_t str = (size_t)K * 2;
    const char* Ab = (const char*)A;
    const char* Bb = (const char*)B;

    for (int kk = 0; kk < ksteps; kk++) {
        if (kk) __syncthreads();                 // prev compute done with LDS
        const size_t koff = (size_t)(kbeg + kk * 64) * 2;
        #pragma unroll
        for (int t = 0; t < 4; t++) {
            const int row = wave * 32 + t * 8 + lrow;
            stage16(Ab + (size_t)(m0 + row) * str + koff + sb,
                    (char*)As + row * 128 + lchk * 16);
            stage16(Bb + (size_t)(n0 + row) * str + koff + sb,
                    (char*)Bs + row * 128 + lchk * 16);
        }
        __syncthreads();                          // staging visible (vmcnt drain)

        #pragma unroll
        for (int ks = 0; ks < 2; ks++) {
            const int ca = ((ks * 4 + quad) ^ (l16 & 7)) * 8;  // swizzled read
            bf16x8 af[4], bfr[4];
            #pragma unroll
            for (int mi = 0; mi < 4; mi++)
                af[mi] = *(const bf16x8*)(&As[(wm + mi * 16 + l16) * 64 + ca]);
            #pragma unroll
            for (int ni = 0; ni < 4; ni++)
                bfr[ni] = *(const bf16x8*)(&Bs[(wn + ni * 16 + l16) * 64 + ca]);
            #pragma unroll
            for (int mi = 0; mi < 4; mi++)
                #pragma unroll
                for (int ni = 0; ni < 4; ni++)
                    acc[mi][ni] = __builtin_amdgcn_mfma_f32_16x16x32_bf16(
                        af[mi], bfr[ni], acc[mi][ni], 0, 0, 0);
        }
    }

    // C/D layout (verified m89/m91): col = lane&15, row = quad*4 + reg
    #pragma unroll
    for (int mi = 0; mi < 4; mi++)
        #pragma unroll
        for (int ni = 0; ni < 4; ni++) {
            const int col = n0 + wn + ni * 16 + l16;
            if (col >= Nlim) continue;
            #pragma unroll
            for (int r = 0; r < 4; r++) {
                const int row = m0 + wm + mi * 16 + quad * 4 + r;
                const float v = acc[mi][ni][r];
                if (OUTMODE == 0)
                    ((__hip_bfloat16*)C)[(size_t)row * Cld + col] = __float2bfloat16(v);
                else if (OUTMODE == 1)
                    ((float*)C)[(size_t)row * Cld + col] = v;
                else
                    atomicAdd(&((float*)C)[(size_t)row * Cld + col], v);
            }
        }
}

// ---------------------------------------------------------------------------
// RMSNorm: f32 input (row stride sx), f32 weight, bf16 out (row stride sy)
// ---------------------------------------------------------------------------
__global__ __launch_bounds__(256)
void rmsnorm_k(const float* __restrict__ X, const float* __restrict__ w,
               __hip_bfloat16* __restrict__ Y, int W, int sx, int sy) {
    int row = blockIdx.x;
    const float* x = X + (size_t)row * sx;
    float ss = 0.f;
    for (int i = threadIdx.x; i < W; i += 256) { float v = x[i]; ss += v * v; }
    for (int off = 32; off; off >>= 1) ss += __shfl_down(ss, off);
    __shared__ float red[4];
    int lane = threadIdx.x & 63, wv = threadIdx.x >> 6;
    if (lane == 0) red[wv] = ss;
    __syncthreads();
    float tot = red[0] + red[1] + red[2] + red[3];
    float inv = rsqrtf(tot / (float)W + 1e-6f);
    for (int i = threadIdx.x; i < W; i += 256) {
        float v = x[i] * inv * w[i];
        Y[(size_t)row * sy + i] = __float2bfloat16(v);
    }
}

// ---------------------------------------------------------------------------
// RoPE (q in-place) + build kf = concat(k_nope, roped k_pe). pos = blockIdx.x.
// ---------------------------------------------------------------------------
__global__ __launch_bounds__(256)
void rope_assemble(__hip_bfloat16* __restrict__ q,           // [S,16,192] in-place
                   const __hip_bfloat16* __restrict__ kvexp, // [S,16,256]
                   const float* __restrict__ kpe_in,         // [S,64]
                   __hip_bfloat16* __restrict__ kf) {        // [S,16,192]
    int s = blockIdx.x;
    int tid = threadIdx.x;
    __shared__ float cs[32], sn[32];
    __shared__ __hip_bfloat16 kpe[64];
    if (tid < 32) {
        float inv = expf(-(float)tid * (logf(10000.0f) / 32.0f));
        float ang = (float)s * inv;
        cs[tid] = cosf(ang);
        sn[tid] = sinf(ang);
    }
    __syncthreads();
    if (tid < 32) {
        float x1 = kpe_in[(size_t)s * 64 + tid];
        float x2 = kpe_in[(size_t)s * 64 + 32 + tid];
        kpe[tid]      = __float2bfloat16(x1 * cs[tid] - x2 * sn[tid]);
        kpe[tid + 32] = __float2bfloat16(x2 * cs[tid] + x1 * sn[tid]);
    }
    for (int p = tid; p < 512; p += 256) {
        int h = p >> 5, j = p & 31;
        size_t base = (size_t)s * 3072 + h * 192 + 128;
        float x1 = __bfloat162float(q[base + j]);
        float x2 = __bfloat162float(q[base + j + 32]);
        q[base + j]      = __float2bfloat16(x1 * cs[j] - x2 * sn[j]);
        q[base + j + 32] = __float2bfloat16(x2 * cs[j] + x1 * sn[j]);
    }
    __syncthreads();
    for (int i = tid; i < 16 * 192; i += 256) {
        int h = i / 192, d = i % 192;
        __hip_bfloat16 v = (d < 128) ? kvexp[(size_t)s * 4096 + h * 256 + d]
                                     : kpe[d - 128];
        kf[(size_t)s * 3072 + h * 192 + d] = v;
    }
}

// ---------------------------------------------------------------------------
// vT[h][d][s] = kvexp[s][h*256 + 128 + d]
// ---------------------------------------------------------------------------
__global__ __launch_bounds__(256)
void transpose_v(const __hip_bfloat16* __restrict__ kvexp,
                 __hip_bfloat16* __restrict__ vT) {
    __shared__ __hip_bfloat16 t[64][65];
    int s0 = blockIdx.x * 64, d0 = blockIdx.y * 64, h = blockIdx.z;
    int c = threadIdx.x & 63;
    int r4 = threadIdx.x >> 6;
    for (int i = 0; i < 16; i++) {
        int r = r4 * 16 + i;
        t[r][c] = kvexp[(size_t)(s0 + r) * 4096 + h * 256 + 128 + d0 + c];
    }
    __syncthreads();
    for (int i = 0; i < 16; i++) {
        int r = r4 * 16 + i;
        vT[((size_t)h * 128 + d0 + r) * 2048 + s0 + c] = t[c][r];
    }
}

// ---------------------------------------------------------------------------
// Flash-style causal attention per (64-row q tile, head). 256 thr = 4 waves.
// ---------------------------------------------------------------------------
__global__ __launch_bounds__(256)
void attn_kernel(const __hip_bfloat16* __restrict__ qb,   // [S,16,192]
                 const __hip_bfloat16* __restrict__ kf,   // [S,16,192]
                 const __hip_bfloat16* __restrict__ vT,   // [16,128,2048]
                 __hip_bfloat16* __restrict__ out) {      // [S,16,128]
    const int h  = blockIdx.y;
    const int qt = blockIdx.x;
    const int q0 = qt * 64;
    const int tid  = threadIdx.x;
    const int wave = tid >> 6;
    const int lane = tid & 63;
    const int quad = lane >> 4;
    const int l16  = lane & 15;

    __shared__ __align__(16) __hip_bfloat16 Ks[128 * 200];
    __shared__ __align__(16) __hip_bfloat16 Vs[128 * 136];
    __shared__ __align__(16) __hip_bfloat16 Ps[64 * 136];

    bf16x8 qfr[6];
    {
        int row = q0 + wave * 16 + l16;
        const __hip_bfloat16* qrow = qb + ((size_t)row * 16 + h) * 192;
        for (int ks = 0; ks < 6; ks++)
            qfr[ks] = *(const bf16x8*)(qrow + ks * 32 + quad * 8);
    }

    f32x4 o_acc[8];
    for (int i = 0; i < 8; i++) o_acc[i] = f32x4{0.f, 0.f, 0.f, 0.f};
    float m_i[4], l_i[4];
    for (int r = 0; r < 4; r++) { m_i[r] = -__builtin_inff(); l_i[r] = 0.f; }

    const float scale = 0.07216878364870322f;  // 192^-0.5
    const int nkt = qt / 2 + 1;

    for (int kt = 0; kt < nkt; kt++) {
        for (int i = 0; i < 12; i++) {
            int lin = i * 2048 + tid * 8;
            int row = lin / 192;
            int col = lin % 192;
            *(uint4*)(&Ks[row * 200 + col]) =
                *(const uint4*)(kf + ((size_t)(kt * 128 + row) * 16 + h) * 192 + col);
        }
        for (int i = 0; i < 8; i++) {
            int lin = i * 2048 + tid * 8;
            int row = lin >> 7;
            int col = lin & 127;
            *(uint4*)(&Vs[row * 136 + col]) =
                *(const uint4*)(vT + ((size_t)h * 128 + row) * 2048 + kt * 128 + col);
        }
        __syncthreads();

        f32x4 sc[8];
        for (int n = 0; n < 8; n++) sc[n] = f32x4{0.f, 0.f, 0.f, 0.f};
        for (int ks = 0; ks < 6; ks++)
            for (int n = 0; n < 8; n++) {
                bf16x8 kb = *(const bf16x8*)(&Ks[(n * 16 + l16) * 200 + ks * 32 + quad * 8]);
                sc[n] = __builtin_amdgcn_mfma_f32_16x16x32_bf16(qfr[ks], kb, sc[n], 0, 0, 0);
            }

        const bool last = (kt == nkt - 1);
        float tmax[4], rsum[4], alpha[4];
        for (int r = 0; r < 4; r++) tmax[r] = -__builtin_inff();
        for (int n = 0; n < 8; n++)
            for (int r = 0; r < 4; r++) {
                float v = sc[n][r] * scale;
                if (last && (kt * 128 + n * 16 + l16) > (q0 + wave * 16 + quad * 4 + r))
                    v = -__builtin_inff();
                sc[n][r] = v;
                tmax[r] = fmaxf(tmax[r], v);
            }
        for (int r = 0; r < 4; r++)
            for (int off = 1; off < 16; off <<= 1)
                tmax[r] = fmaxf(tmax[r], __shfl_xor(tmax[r], off));
        for (int r = 0; r < 4; r++) {
            float mn = fmaxf(m_i[r], tmax[r]);
            alpha[r] = expf(m_i[r] - mn);
            m_i[r] = mn;
            rsum[r] = 0.f;
        }
        for (int n = 0; n < 8; n++)
            for (int r = 0; r < 4; r++) {
                float p = expf(sc[n][r] - m_i[r]);
                sc[n][r] = p;
                rsum[r] += p;
            }
        for (int r = 0; r < 4; r++) {
            for (int off = 1; off < 16; off <<= 1)
                rsum[r] += __shfl_xor(rsum[r], off);
            l_i[r] = l_i[r] * alpha[r] + rsum[r];
        }
        for (int n = 0; n < 8; n++)
            for (int r = 0; r < 4; r++)
                Ps[(wave * 16 + quad * 4 + r) * 136 + n * 16 + l16] =
                    __float2bfloat16(sc[n][r]);
        for (int d = 0; d < 8; d++)
            for (int r = 0; r < 4; r++)
                o_acc[d][r] *= alpha[r];
        __syncthreads();

        for (int ks2 = 0; ks2 < 4; ks2++) {
            bf16x8 pa = *(const bf16x8*)(&Ps[(wave * 16 + l16) * 136 + ks2 * 32 + quad * 8]);
            for (int d = 0; d < 8; d++) {
                bf16x8 vb = *(const bf16x8*)(&Vs[(d * 16 + l16) * 136 + ks2 * 32 + quad * 8]);
                o_acc[d] = __builtin_amdgcn_mfma_f32_16x16x32_bf16(pa, vb, o_acc[d], 0, 0, 0);
            }
        }
        __syncthreads();
    }

    for (int d = 0; d < 8; d++)
        for (int r = 0; r < 4; r++) {
            int row = q0 + wave * 16 + quad * 4 + r;
            float v = o_acc[d][r] / l_i[r];
            out[((size_t)row * 16 + h) * 128 + d * 16 + l16] = __float2bfloat16(v);
        }
}

// ---------------------------------------------------------------------------
extern "C" void kernel_launch(void* const* d_in, const int* in_sizes, int n_in,
                              void* d_out, int out_size, void* d_ws, size_t ws_size,
                              hipStream_t stream) {
    const float* hidden = (const float*)d_in[0];
    const float* wq_a   = (const float*)d_in[2];
    const float* q_a_w  = (const float*)d_in[3];
    const float* wq_b   = (const float*)d_in[4];
    const float* wkv_a  = (const float*)d_in[5];
    const float* kv_a_w = (const float*)d_in[6];
    const float* wkv_b  = (const float*)d_in[7];
    const float* wo     = (const float*)d_in[8];
    float* out = (float*)d_out;

    char* ws = (char*)d_ws;
    // Region map (lifetimes sequential; peak 58 MB):
    __hip_bfloat16* hiddenB = (__hip_bfloat16*)(ws + 0);          // [2048,4096]   s0-s1
    __hip_bfloat16* wq_bB   = (__hip_bfloat16*)(ws + 0);          // [3072,1536]   s3-s4
    __hip_bfloat16* kfB     = (__hip_bfloat16*)(ws + 0);          // [2048,16,192] s6-s8
    __hip_bfloat16* W0      = (__hip_bfloat16*)(ws + 16777216);   // [2176,4096]   s0-s1
    __hip_bfloat16* kv_exp  = (__hip_bfloat16*)(ws + 16777216);   // [2048,16,256] s5-s7
    __hip_bfloat16* attn_o  = (__hip_bfloat16*)(ws + 16777216);   // [2048,2048]   s8-s9
    float*          fused   = (float*)(ws + 34603008);            // [2048,2112]   s1-s2
    __hip_bfloat16* qb      = (__hip_bfloat16*)(ws + 34603008);   // [2048,16,192] s4-s8
    __hip_bfloat16* woB     = (__hip_bfloat16*)(ws + 34603008);   // [4096,2048]   s9
    __hip_bfloat16* wkv_bB  = (__hip_bfloat16*)(ws + 47185920);   // [4096,512]    s3-s5
    float*          kpe     = (float*)(ws + 51904512);            // [2048,64]     s2-s6
    __hip_bfloat16* q_lat   = (__hip_bfloat16*)(ws + 52428800);   // [2048,1536]   s2-s4
    __hip_bfloat16* vT      = (__hip_bfloat16*)(ws + 52428800);   // [16,128,2048] s7-s8
    __hip_bfloat16* ckv     = (__hip_bfloat16*)(ws + 58720256);   // [2048,512]    s2-s5

    dim3 blk(256);
    // s0: operand conversion
    cvt_bf16<<<8192, blk, 0, stream>>>(hidden, hiddenB, 2097152);
    cvt_bf16<<<6144, blk, 0, stream>>>(wq_a,  W0,                1572864);
    cvt_bf16<<<2304, blk, 0, stream>>>(wkv_a, W0 + 1536 * 4096,   589824);
    zero_u4<<<128, blk, 0, stream>>>((uint4*)(W0 + 2112 * 4096), 32768);  // pad rows
    // s1: fused first-stage GEMM, split-K=4, atomic accumulate
    zero_f32<<<4224, blk, 0, stream>>>(fused, 1081344);
    gemm_lds<2><<<dim3(17, 16, 4), blk, 0, stream>>>(hiddenB, W0, fused, 4096, 2112, 2112, 16);
    // s2: compact k_pe, RMSNorms
    kpe_copy<<<512, blk, 0, stream>>>(fused, kpe);
    rmsnorm_k<<<2048, blk, 0, stream>>>(fused,        q_a_w,  q_lat, 1536, 2112, 1536);
    rmsnorm_k<<<2048, blk, 0, stream>>>(fused + 1536, kv_a_w, ckv,    512, 2112,  512);
    // s3: second-stage weight conversion (aliases dead hiddenB / fused tail)
    cvt_bf16<<<4608, blk, 0, stream>>>(wq_b,  wq_bB,  1179648);
    cvt_bf16<<<2048, blk, 0, stream>>>(wkv_b, wkv_bB,  524288);
    // s4/s5: up-projections
    gemm_lds<0><<<dim3(24, 16), blk, 0, stream>>>(q_lat, wq_bB,  qb,     1536, 3072, 3072, 24);
    gemm_lds<0><<<dim3(32, 16), blk, 0, stream>>>(ckv,   wkv_bB, kv_exp,  512, 4096, 4096,  8);
    // s6/s7: RoPE + K assembly, V transpose
    rope_assemble<<<2048, blk, 0, stream>>>(qb, kv_exp, kpe, kfB);
    transpose_v<<<dim3(32, 2, 16), blk, 0, stream>>>(kv_exp, vT);
    // s8: attention
    attn_kernel<<<dim3(32, 16), blk, 0, stream>>>(qb, kfB, vT, attn_o);
    // s9: output projection
    cvt_bf16<<<8192, blk, 0, stream>>>(wo, woB, 2097152);
    gemm_lds<1><<<dim3(32, 16), blk, 0, stream>>>(attn_o, woB, out, 2048, 4096, 4096, 32);
}

// Round 6
// 496.716 us; speedup vs baseline: 2.1048x; 1.0493x over previous
//
#include <hip/hip_runtime.h>
#include <hip/hip_bf16.h>

// MLA prefill: B=1, S=2048, H=4096, NH=16, QK_NOPE=128, QK_ROPE=64, V=128
// f32 device tensors; bf16 MFMA internally. Attention: K-tile 64, k-major
// 16B-cell LDS (conflict-free b128), global_load_lds staging, 3 blocks/CU.

typedef short bf16x8 __attribute__((ext_vector_type(8)));
typedef float f32x4  __attribute__((ext_vector_type(4)));

#if __has_builtin(__builtin_amdgcn_global_load_lds)
#define USE_GLL 1
#else
#define USE_GLL 0
#endif

__device__ __forceinline__ void stage16(const void* g, void* l) {
#if USE_GLL
    __builtin_amdgcn_global_load_lds(
        (__attribute__((address_space(1))) void*)(g),
        (__attribute__((address_space(3))) void*)(l), 16, 0, 0);
#else
    *(uint4*)l = *(const uint4*)g;
#endif
}

#define LOG2E 1.4426950408889634f

__device__ __forceinline__ short bf16_bits(float v) {
    union { __hip_bfloat16 h; short s; } u;
    u.h = __float2bfloat16(v);
    return u.s;
}

// ---------------------------------------------------------------------------
// Elementwise helpers
// ---------------------------------------------------------------------------
__global__ __launch_bounds__(256)
void cvt_bf16(const float* __restrict__ s, __hip_bfloat16* __restrict__ d, int nq) {
    int i = blockIdx.x * 256 + threadIdx.x;
    if (i >= nq) return;
    float4 v = ((const float4*)s)[i];
    union { uint2 u; __hip_bfloat16 h[4]; } r;
    r.h[0] = __float2bfloat16(v.x); r.h[1] = __float2bfloat16(v.y);
    r.h[2] = __float2bfloat16(v.z); r.h[3] = __float2bfloat16(v.w);
    ((uint2*)d)[i] = r.u;
}

__global__ __launch_bounds__(256)
void zero_f32(float* __restrict__ p, int n4) {
    int i = blockIdx.x * 256 + threadIdx.x;
    if (i < n4) ((float4*)p)[i] = float4{0.f, 0.f, 0.f, 0.f};
}

__global__ __launch_bounds__(256)
void zero_u4(uint4* __restrict__ p, int n) {
    int i = blockIdx.x * 256 + threadIdx.x;
    if (i < n) p[i] = make_uint4(0u, 0u, 0u, 0u);
}

__global__ __launch_bounds__(256)
void kpe_copy(const float* __restrict__ fused, float* __restrict__ kpe) {
    int i = blockIdx.x * 256 + threadIdx.x;   // 131072 total
    int r = i >> 6, c = i & 63;
    kpe[i] = fused[(size_t)r * 2112 + 2048 + c];
}

// ---------------------------------------------------------------------------
// m97-style GEMM: C = A[M,K] * B[*,K]^T, bf16 in, fp32 acc, 128x128 tile.
// global_load_lds 16B staging with XOR source swizzle; conflict-free reads.
// OUTMODE: 0 = bf16 store, 1 = f32 store, 2 = f32 atomicAdd (split-K).
// ---------------------------------------------------------------------------
template<int OUTMODE>
__global__ __launch_bounds__(256)
void gemm_lds(const __hip_bfloat16* __restrict__ A,
              const __hip_bfloat16* __restrict__ B,
              void* __restrict__ C,
              int K, int Cld, int Nlim, int ksteps) {
    __shared__ __align__(16) short As[128 * 64];
    __shared__ __align__(16) short Bs[128 * 64];

    const int tid  = threadIdx.x;
    const int lane = tid & 63;
    const int wave = tid >> 6;
    const int quad = lane >> 4;
    const int l16  = lane & 15;
    const int m0 = blockIdx.y * 128;
    const int n0 = blockIdx.x * 128;
    const int wm = (wave >> 1) * 64;
    const int wn = (wave & 1) * 64;
    const int kbeg = blockIdx.z * ksteps * 64;

    const int lrow = lane >> 3;
    const int lchk = lane & 7;
    const int sb   = (lchk ^ lrow) * 16;

    f32x4 acc[4][4];
    #pragma unroll
    for (int i = 0; i < 4; i++)
        #pragma unroll
        for (int j = 0; j < 4; j++)
            acc[i][j] = f32x4{0.f, 0.f, 0.f, 0.f};

    const size_t str = (size_t)K * 2;
    const char* Ab = (const char*)A;
    const char* Bb = (const char*)B;

    for (int kk = 0; kk < ksteps; kk++) {
        if (kk) __syncthreads();
        const size_t koff = (size_t)(kbeg + kk * 64) * 2;
        #pragma unroll
        for (int t = 0; t < 4; t++) {
            const int row = wave * 32 + t * 8 + lrow;
            stage16(Ab + (size_t)(m0 + row) * str + koff + sb,
                    (char*)As + row * 128 + lchk * 16);
            stage16(Bb + (size_t)(n0 + row) * str + koff + sb,
                    (char*)Bs + row * 128 + lchk * 16);
        }
        __syncthreads();

        #pragma unroll
        for (int ks = 0; ks < 2; ks++) {
            const int ca = ((ks * 4 + quad) ^ (l16 & 7)) * 8;
            bf16x8 af[4], bfr[4];
            #pragma unroll
            for (int mi = 0; mi < 4; mi++)
                af[mi] = *(const bf16x8*)(&As[(wm + mi * 16 + l16) * 64 + ca]);
            #pragma unroll
            for (int ni = 0; ni < 4; ni++)
                bfr[ni] = *(const bf16x8*)(&Bs[(wn + ni * 16 + l16) * 64 + ca]);
            #pragma unroll
            for (int mi = 0; mi < 4; mi++)
                #pragma unroll
                for (int ni = 0; ni < 4; ni++)
                    acc[mi][ni] = __builtin_amdgcn_mfma_f32_16x16x32_bf16(
                        af[mi], bfr[ni], acc[mi][ni], 0, 0, 0);
        }
    }

    #pragma unroll
    for (int mi = 0; mi < 4; mi++)
        #pragma unroll
        for (int ni = 0; ni < 4; ni++) {
            const int col = n0 + wn + ni * 16 + l16;
            if (col >= Nlim) continue;
            #pragma unroll
            for (int r = 0; r < 4; r++) {
                const int row = m0 + wm + mi * 16 + quad * 4 + r;
                const float v = acc[mi][ni][r];
                if (OUTMODE == 0)
                    ((__hip_bfloat16*)C)[(size_t)row * Cld + col] = __float2bfloat16(v);
                else if (OUTMODE == 1)
                    ((float*)C)[(size_t)row * Cld + col] = v;
                else
                    atomicAdd(&((float*)C)[(size_t)row * Cld + col], v);
            }
        }
}

// ---------------------------------------------------------------------------
__global__ __launch_bounds__(256)
void rmsnorm_k(const float* __restrict__ X, const float* __restrict__ w,
               __hip_bfloat16* __restrict__ Y, int W, int sx, int sy) {
    int row = blockIdx.x;
    const float* x = X + (size_t)row * sx;
    float ss = 0.f;
    for (int i = threadIdx.x; i < W; i += 256) { float v = x[i]; ss += v * v; }
    for (int off = 32; off; off >>= 1) ss += __shfl_down(ss, off);
    __shared__ float red[4];
    int lane = threadIdx.x & 63, wv = threadIdx.x >> 6;
    if (lane == 0) red[wv] = ss;
    __syncthreads();
    float tot = red[0] + red[1] + red[2] + red[3];
    float inv = rsqrtf(tot / (float)W + 1e-6f);
    for (int i = threadIdx.x; i < W; i += 256) {
        float v = x[i] * inv * w[i];
        Y[(size_t)row * sy + i] = __float2bfloat16(v);
    }
}

// ---------------------------------------------------------------------------
// RoPE (q in-place) + build kfT[h][c][s]: 16B cell c holds k=c*8..c*8+7.
// ---------------------------------------------------------------------------
__global__ __launch_bounds__(256)
void rope_assemble(__hip_bfloat16* __restrict__ q,           // [S,16,192] in-place
                   const __hip_bfloat16* __restrict__ kvexp, // [S,16,256]
                   const float* __restrict__ kpe_in,         // [S,64]
                   __hip_bfloat16* __restrict__ kfT) {       // [16][24][2048] cells
    int s = blockIdx.x;
    int tid = threadIdx.x;
    __shared__ float cs[32], sn[32];
    __shared__ __hip_bfloat16 kpe[64];
    if (tid < 32) {
        float inv = expf(-(float)tid * (logf(10000.0f) / 32.0f));
        float ang = (float)s * inv;
        cs[tid] = cosf(ang);
        sn[tid] = sinf(ang);
    }
    __syncthreads();
    if (tid < 32) {
        float x1 = kpe_in[(size_t)s * 64 + tid];
        float x2 = kpe_in[(size_t)s * 64 + 32 + tid];
        kpe[tid]      = __float2bfloat16(x1 * cs[tid] - x2 * sn[tid]);
        kpe[tid + 32] = __float2bfloat16(x2 * cs[tid] + x1 * sn[tid]);
    }
    for (int p = tid; p < 512; p += 256) {
        int h = p >> 5, j = p & 31;
        size_t base = (size_t)s * 3072 + h * 192 + 128;
        float x1 = __bfloat162float(q[base + j]);
        float x2 = __bfloat162float(q[base + j + 32]);
        q[base + j]      = __float2bfloat16(x1 * cs[j] - x2 * sn[j]);
        q[base + j + 32] = __float2bfloat16(x2 * cs[j] + x1 * sn[j]);
    }
    __syncthreads();
    for (int i = tid; i < 16 * 192; i += 256) {
        int h = i / 192, d = i % 192;
        __hip_bfloat16 v = (d < 128) ? kvexp[(size_t)s * 4096 + h * 256 + d]
                                     : kpe[d - 128];
        kfT[((size_t)(h * 24 + (d >> 3)) * 2048 + s) * 8 + (d & 7)] = v;
    }
}

// ---------------------------------------------------------------------------
// vT2[h][sc][d]: 16B cell holds V[s=sc*8..sc*8+7][d] transposed per 8-s group.
// ---------------------------------------------------------------------------
__global__ __launch_bounds__(256)
void transpose_v(const __hip_bfloat16* __restrict__ kvexp,
                 __hip_bfloat16* __restrict__ vT2) {
    __shared__ short t[64 * 72];
    int s0 = blockIdx.x * 64, d0 = blockIdx.y * 64, h = blockIdx.z;
    int c = threadIdx.x & 63;
    int r4 = threadIdx.x >> 6;
    for (int i = 0; i < 16; i++) {
        int r = r4 * 16 + i;
        t[r * 72 + c] = *(const short*)&kvexp[(size_t)(s0 + r) * 4096 + h * 256 + 128 + d0 + c];
    }
    __syncthreads();
    for (int it = 0; it < 2; it++) {
        int scl = it * 4 + (threadIdx.x >> 6);  // 0..7 local s-chunk
        int d   = threadIdx.x & 63;
        union { uint4 u; short sh[8]; } pk;
        #pragma unroll
        for (int e = 0; e < 8; e++) pk.sh[e] = t[(scl * 8 + e) * 72 + d];
        size_t cell = ((size_t)h * 256 + blockIdx.x * 8 + scl) * 128 + d0 + d;
        ((uint4*)vT2)[cell] = pk.u;
    }
}

// ---------------------------------------------------------------------------
// Flash attention: q-tile 64, K-tile 64, 4 waves, 48KB LDS -> 3 blocks/CU.
// k-major 16B-cell LDS layouts, conflict-free b128 reads.
// ---------------------------------------------------------------------------
__global__ __launch_bounds__(256, 3)
void attn_kernel(const __hip_bfloat16* __restrict__ qb,   // [S,16,192]
                 const __hip_bfloat16* __restrict__ kfT,  // [16][24][2048] cells
                 const __hip_bfloat16* __restrict__ vT2,  // [16][256][128] cells
                 __hip_bfloat16* __restrict__ out) {      // [S,16,128]
    const int h  = blockIdx.y;
    const int qt = 31 - blockIdx.x;       // heavy tiles first
    const int q0 = qt * 64;
    const int tid  = threadIdx.x;
    const int wave = tid >> 6;
    const int lane = tid & 63;
    const int quad = lane >> 4;
    const int l16  = lane & 15;

    __shared__ __align__(16) short Ks2[24 * 64 * 8];   // 24 KB
    __shared__ __align__(16) short Vs2[ 8 * 128 * 8];  // 16 KB
    __shared__ __align__(16) short Ps2[ 8 * 64 * 8];   //  8 KB

    const float scale = 0.07216878364870322f;  // 192^-0.5

    // Q fragments, pre-scaled: A[m=l16][k=quad*8+j]
    bf16x8 qfr[6];
    {
        int row = q0 + wave * 16 + l16;
        const __hip_bfloat16* qrow = qb + ((size_t)row * 16 + h) * 192;
        for (int ks = 0; ks < 6; ks++) {
            union { bf16x8 v; __hip_bfloat16 h8[8]; } u;
            u.v = *(const bf16x8*)(qrow + ks * 32 + quad * 8);
            #pragma unroll
            for (int e = 0; e < 8; e++)
                u.h8[e] = __float2bfloat16(__bfloat162float(u.h8[e]) * scale);
            qfr[ks] = u.v;
        }
    }

    f32x4 o_acc[8];
    #pragma unroll
    for (int i = 0; i < 8; i++) o_acc[i] = f32x4{0.f, 0.f, 0.f, 0.f};
    float m_i[4], l_i[4];
    #pragma unroll
    for (int r = 0; r < 4; r++) { m_i[r] = -__builtin_inff(); l_i[r] = 0.f; }

    const char* kfb = (const char*)kfT;
    const char* vtb = (const char*)vT2;

    for (int kt = 0; kt <= qt; kt++) {
        if (kt) __syncthreads();
        // stage K: wave handles k-chunk columns c = wave*6 .. +5
        #pragma unroll
        for (int j = 0; j < 6; j++) {
            int c = wave * 6 + j;
            stage16(kfb + (((size_t)(h * 24 + c) * 2048) + kt * 64 + lane) * 16,
                    (char*)Ks2 + (c * 64 + lane) * 16);
        }
        // stage V: wave handles s-chunk columns c = wave*2, wave*2+1 (two halves)
        #pragma unroll
        for (int j = 0; j < 4; j++) {
            int c  = wave * 2 + (j >> 1);
            int hd = j & 1;
            stage16(vtb + (((size_t)(h * 256 + kt * 8 + c) * 128) + hd * 64 + lane) * 16,
                    (char*)Vs2 + (c * 128 + hd * 64 + lane) * 16);
        }
        __syncthreads();

        // scores: 16 q-rows x 64 keys per wave
        f32x4 sc[4];
        #pragma unroll
        for (int n = 0; n < 4; n++) sc[n] = f32x4{0.f, 0.f, 0.f, 0.f};
        #pragma unroll
        for (int ks = 0; ks < 6; ks++)
            #pragma unroll
            for (int n = 0; n < 4; n++) {
                bf16x8 kb = *(const bf16x8*)(&Ks2[((ks * 4 + quad) * 64 + n * 16 + l16) * 8]);
                sc[n] = __builtin_amdgcn_mfma_f32_16x16x32_bf16(qfr[ks], kb, sc[n], 0, 0, 0);
            }

        const bool last = (kt == qt);
        float tmax[4], rsum[4], alpha[4];
        #pragma unroll
        for (int r = 0; r < 4; r++) tmax[r] = -__builtin_inff();
        #pragma unroll
        for (int n = 0; n < 4; n++)
            #pragma unroll
            for (int r = 0; r < 4; r++) {
                float v = sc[n][r];
                if (last && (kt * 64 + n * 16 + l16) > (q0 + wave * 16 + quad * 4 + r))
                    v = -__builtin_inff();
                sc[n][r] = v;
                tmax[r] = fmaxf(tmax[r], v);
            }
        #pragma unroll
        for (int r = 0; r < 4; r++)
            #pragma unroll
            for (int off = 1; off < 16; off <<= 1)
                tmax[r] = fmaxf(tmax[r], __shfl_xor(tmax[r], off));
        #pragma unroll
        for (int r = 0; r < 4; r++) {
            float mn = fmaxf(m_i[r], tmax[r]);
            alpha[r] = exp2f((m_i[r] - mn) * LOG2E);   // 0 on first tile
            m_i[r] = mn;
            rsum[r] = 0.f;
        }
        #pragma unroll
        for (int n = 0; n < 4; n++)
            #pragma unroll
            for (int r = 0; r < 4; r++) {
                float p = exp2f((sc[n][r] - m_i[r]) * LOG2E);
                sc[n][r] = p;
                rsum[r] += p;
            }
        #pragma unroll
        for (int r = 0; r < 4; r++) {
            #pragma unroll
            for (int off = 1; off < 16; off <<= 1)
                rsum[r] += __shfl_xor(rsum[r], off);
            l_i[r] = l_i[r] * alpha[r] + rsum[r];
        }
        // P -> LDS (k-major cells): row = wave*16+quad*4+r, key col = n*16+l16
        #pragma unroll
        for (int n = 0; n < 4; n++)
            #pragma unroll
            for (int r = 0; r < 4; r++)
                Ps2[((n * 2 + (l16 >> 3)) * 64 + wave * 16 + quad * 4 + r) * 8 + (l16 & 7)] =
                    bf16_bits(sc[n][r]);
        #pragma unroll
        for (int d = 0; d < 8; d++)
            #pragma unroll
            for (int r = 0; r < 4; r++)
                o_acc[d][r] *= alpha[r];
        // Ps2 rows are wave-private; compiler's lgkmcnt covers write->read
        #pragma unroll
        for (int ks2 = 0; ks2 < 2; ks2++) {
            bf16x8 pa = *(const bf16x8*)(&Ps2[((ks2 * 4 + quad) * 64 + wave * 16 + l16) * 8]);
            #pragma unroll
            for (int dg = 0; dg < 8; dg++) {
                bf16x8 vb = *(const bf16x8*)(&Vs2[((ks2 * 4 + quad) * 128 + dg * 16 + l16) * 8]);
                o_acc[dg] = __builtin_amdgcn_mfma_f32_16x16x32_bf16(pa, vb, o_acc[dg], 0, 0, 0);
            }
        }
    }

    #pragma unroll
    for (int dg = 0; dg < 8; dg++)
        #pragma unroll
        for (int r = 0; r < 4; r++) {
            int row = q0 + wave * 16 + quad * 4 + r;
            float v = o_acc[dg][r] / l_i[r];
            out[((size_t)row * 16 + h) * 128 + dg * 16 + l16] = __float2bfloat16(v);
        }
}

// ---------------------------------------------------------------------------
extern "C" void kernel_launch(void* const* d_in, const int* in_sizes, int n_in,
                              void* d_out, int out_size, void* d_ws, size_t ws_size,
                              hipStream_t stream) {
    const float* hidden = (const float*)d_in[0];
    const float* wq_a   = (const float*)d_in[2];
    const float* q_a_w  = (const float*)d_in[3];
    const float* wq_b   = (const float*)d_in[4];
    const float* wkv_a  = (const float*)d_in[5];
    const float* kv_a_w = (const float*)d_in[6];
    const float* wkv_b  = (const float*)d_in[7];
    const float* wo     = (const float*)d_in[8];
    float* out = (float*)d_out;

    char* ws = (char*)d_ws;
    __hip_bfloat16* hiddenB = (__hip_bfloat16*)(ws + 0);          // [2048,4096]   s0-s1
    __hip_bfloat16* wq_bB   = (__hip_bfloat16*)(ws + 0);          // [3072,1536]   s3-s4
    __hip_bfloat16* kfT     = (__hip_bfloat16*)(ws + 0);          // [16][24][2048]c s6-s8
    __hip_bfloat16* W0      = (__hip_bfloat16*)(ws + 16777216);   // [2176,4096]   s0-s1
    __hip_bfloat16* kv_exp  = (__hip_bfloat16*)(ws + 16777216);   // [2048,16,256] s5-s7
    __hip_bfloat16* attn_o  = (__hip_bfloat16*)(ws + 16777216);   // [2048,2048]   s8-s9
    float*          fused   = (float*)(ws + 34603008);            // [2048,2112]   s1-s2
    __hip_bfloat16* qb      = (__hip_bfloat16*)(ws + 34603008);   // [2048,16,192] s4-s8
    __hip_bfloat16* woB     = (__hip_bfloat16*)(ws + 34603008);   // [4096,2048]   s9
    __hip_bfloat16* wkv_bB  = (__hip_bfloat16*)(ws + 47185920);   // [4096,512]    s3-s5
    float*          kpe     = (float*)(ws + 51904512);            // [2048,64]     s2-s6
    __hip_bfloat16* q_lat   = (__hip_bfloat16*)(ws + 52428800);   // [2048,1536]   s2-s4
    __hip_bfloat16* vT2     = (__hip_bfloat16*)(ws + 52428800);   // [16][256][128]c s7-s8
    __hip_bfloat16* ckv     = (__hip_bfloat16*)(ws + 58720256);   // [2048,512]    s2-s5

    dim3 blk(256);
    cvt_bf16<<<8192, blk, 0, stream>>>(hidden, hiddenB, 2097152);
    cvt_bf16<<<6144, blk, 0, stream>>>(wq_a,  W0,               1572864);
    cvt_bf16<<<2304, blk, 0, stream>>>(wkv_a, W0 + 1536 * 4096,  589824);
    zero_u4<<<128, blk, 0, stream>>>((uint4*)(W0 + 2112 * 4096), 32768);
    zero_f32<<<4224, blk, 0, stream>>>(fused, 1081344);
    gemm_lds<2><<<dim3(17, 16, 4), blk, 0, stream>>>(hiddenB, W0, fused, 4096, 2112, 2112, 16);
    kpe_copy<<<512, blk, 0, stream>>>(fused, kpe);
    rmsnorm_k<<<2048, blk, 0, stream>>>(fused,        q_a_w,  q_lat, 1536, 2112, 1536);
    rmsnorm_k<<<2048, blk, 0, stream>>>(fused + 1536, kv_a_w, ckv,    512, 2112,  512);
    cvt_bf16<<<4608, blk, 0, stream>>>(wq_b,  wq_bB,  1179648);
    cvt_bf16<<<2048, blk, 0, stream>>>(wkv_b, wkv_bB,  524288);
    gemm_lds<0><<<dim3(24, 16), blk, 0, stream>>>(q_lat, wq_bB,  qb,     1536, 3072, 3072, 24);
    gemm_lds<0><<<dim3(32, 16), blk, 0, stream>>>(ckv,   wkv_bB, kv_exp,  512, 4096, 4096,  8);
    rope_assemble<<<2048, blk, 0, stream>>>(qb, kv_exp, kpe, kfT);
    transpose_v<<<dim3(32, 2, 16), blk, 0, stream>>>(kv_exp, vT2);
    attn_kernel<<<dim3(32, 16), blk, 0, stream>>>(qb, kfT, vT2, attn_o);
    cvt_bf16<<<8192, blk, 0, stream>>>(wo, woB, 2097152);
    gemm_lds<1><<<dim3(32, 16), blk, 0, stream>>>(attn_o, woB, out, 2048, 4096, 4096, 32);
}